// Round 1
// baseline (57.731 us; speedup 1.0000x reference)
//
#include <hip/hip_runtime.h>
#include <hip/hip_bf16.h>
#include <math.h>

#define KN 8192
#define DEG 32
#define EE (KN*DEG)

// VAR = float32(10^(-19.9) * 5000000 / 10)
#define VAR_F 6.294627058970831e-15f

// Kernel 1: fused 3x conv + head. One wave (64 lanes) per node.
// Lane roles: i = lane&31 (output channel of msg MLP / h channel j),
//             g = lane>>5 (edge-half group).
__global__ __launch_bounds__(256) void mpnn_fused(
    const float* __restrict__ x,
    const float* __restrict__ edge_attr,
    const float* __restrict__ Wm1, const float* __restrict__ bm1,
    const float* __restrict__ Wm2, const float* __restrict__ bm2,
    const float* __restrict__ Wu1, const float* __restrict__ bu1,
    const float* __restrict__ Wu2, const float* __restrict__ bu2,
    const float* __restrict__ Wh1, const float* __restrict__ bh1,
    const float* __restrict__ Wh2, const float* __restrict__ bh2,
    float* __restrict__ p_out)
{
    __shared__ float h_lds[4][32*32];  // per-wave h tile
    __shared__ float a_lds[4][32];     // per-wave edge_attr
    __shared__ float xt[4][44];        // [0..8]=x, [9..40]=aggr
    __shared__ float ubuf[4][16];      // u vector

    const int w    = threadIdx.x >> 6;
    const int lane = threadIdx.x & 63;
    const int i    = lane & 31;
    const int g    = lane >> 5;
    const int k    = blockIdx.x * 4 + w;

    // ---- register preload (weights used 3x across convs) ----
    float wm1[10];
    #pragma unroll
    for (int d = 0; d < 10; ++d) wm1[d] = Wm1[k*320 + d*32 + i];
    const float bm1_i = bm1[k*32 + i];

    float wm2[32];
    #pragma unroll
    for (int j = 0; j < 32; ++j) wm2[j] = Wm2[k*1024 + j*32 + i];
    const float bm2_i = bm2[k*32 + i];

    const int m  = lane & 15;
    const int dg = lane >> 4;       // 0..3, update-MLP d-group
    float wu1[11];
    #pragma unroll
    for (int t = 0; t < 11; ++t) {
        int d = dg*11 + t;
        wu1[t] = (d < 41) ? Wu1[k*656 + d*16 + m] : 0.f;
    }
    const float bu1_m = bu1[k*16 + m];

    const int o  = lane & 7;
    const int mg = lane >> 3;       // 0..7, comb m-group
    const float wu2a = Wu2[k*128 + (mg*2+0)*8 + o];
    const float wu2b = Wu2[k*128 + (mg*2+1)*8 + o];
    const float bu2_o = bu2[k*8 + o];

    float wh1[8];
    #pragma unroll
    for (int d = 0; d < 8; ++d) wh1[d] = Wh1[k*128 + d*16 + m];
    const float bh1_m = bh1[k*16 + m];
    const float wh2_m = Wh2[k*16 + m];
    const float bh2_k = bh2[k];

    // ---- node state ----
    if (lane < 9)  xt[w][lane]    = x[k*9 + lane];
    if (lane < 32) a_lds[w][lane] = edge_attr[k*32 + lane];
    __syncthreads();

    float* h = h_lds[w];

    for (int it = 0; it < 3; ++it) {
        // c_j = bm1_j + sum_d x_d * Wm1[d][j]   (j = i)
        float c = bm1_i;
        #pragma unroll
        for (int d = 0; d < 9; ++d) c = fmaf(xt[w][d], wm1[d], c);

        // h[e][j] = relu(c_j + a_e * Wm1[9][j])
        #pragma unroll
        for (int eg = 0; eg < 16; ++eg) {
            int e = g*16 + eg;
            float hv = fmaf(a_lds[w][e], wm1[9], c);
            h[e*32 + i] = fmaxf(hv, 0.f);
        }
        __syncthreads();

        // msg GEMM + aggregate: aggr_i = sum_e relu(bm2_i + sum_j h[e][j]*Wm2[j][i])
        float aggr = 0.f;
        #pragma unroll 4
        for (int eg = 0; eg < 16; ++eg) {
            int e = g*16 + eg;
            const float4* h4 = (const float4*)(h + e*32);
            float acc0 = bm2_i, acc1 = 0.f;
            #pragma unroll
            for (int jj = 0; jj < 4; ++jj) {
                float4 ha = h4[jj];
                float4 hb = h4[jj+4];
                acc0 = fmaf(ha.x, wm2[jj*4+0], acc0);
                acc0 = fmaf(ha.y, wm2[jj*4+1], acc0);
                acc0 = fmaf(ha.z, wm2[jj*4+2], acc0);
                acc0 = fmaf(ha.w, wm2[jj*4+3], acc0);
                acc1 = fmaf(hb.x, wm2[16+jj*4+0], acc1);
                acc1 = fmaf(hb.y, wm2[16+jj*4+1], acc1);
                acc1 = fmaf(hb.z, wm2[16+jj*4+2], acc1);
                acc1 = fmaf(hb.w, wm2[16+jj*4+3], acc1);
            }
            aggr += fmaxf(acc0 + acc1, 0.f);
        }
        aggr += __shfl_xor(aggr, 32);
        __syncthreads();
        if (g == 0) xt[w][9 + i] = aggr;
        __syncthreads();

        // u_m = relu(bu1_m + sum_{d<41} t_d * Wu1[d][m]); t = [x(9), aggr(32)]
        float up = 0.f;
        #pragma unroll
        for (int t = 0; t < 11; ++t) {
            int d = dg*11 + t;
            if (d < 41) up = fmaf(xt[w][d], wu1[t], up);
        }
        up += __shfl_xor(up, 16);
        up += __shfl_xor(up, 32);
        float u = fmaxf(up + bu1_m, 0.f);
        if (lane < 16) ubuf[w][lane] = u;
        __syncthreads();

        // comb_o = relu(bu2_o + sum_m u_m * Wu2[m][o])
        float cp = wu2a * ubuf[w][mg*2] + wu2b * ubuf[w][mg*2+1];
        cp += __shfl_xor(cp, 8);
        cp += __shfl_xor(cp, 16);
        cp += __shfl_xor(cp, 32);
        float comb = fmaxf(cp + bu2_o, 0.f);
        __syncthreads();                 // all xt readers done
        if (lane < 8) xt[w][1 + lane] = comb;  // x_new = [x0, comb]
        __syncthreads();
    }

    // head: hh_m = relu(bh1_m + sum_d emb_d*Wh1[d][m]); p = sigmoid(sum hh*Wh2 + bh2)
    float hp = 0.f;
    #pragma unroll
    for (int d = 0; d < 8; ++d) hp = fmaf(xt[w][1+d], wh1[d], hp);
    float hh = fmaxf(hp + bh1_m, 0.f);
    float pp = hh * wh2_m;
    pp += __shfl_xor(pp, 1);
    pp += __shfl_xor(pp, 2);
    pp += __shfl_xor(pp, 4);
    pp += __shfl_xor(pp, 8);
    float z = pp + bh2_k;
    float p = 1.f / (1.f + expf(-z));
    if (lane == 0) p_out[k] = p;
}

// Kernel 2: interference + rate. 32 lanes per node.
__global__ __launch_bounds__(256) void mpnn_interf(
    const float* __restrict__ H,
    const int* __restrict__ edge_index,
    const float* __restrict__ p,
    float* __restrict__ out)
{
    const int t = blockIdx.x * 256 + threadIdx.x;
    const int s = t >> 5;
    const int e = t & 31;
    const int* dst = edge_index + EE;
    const int d = dst[s*DEG + e];
    float part = p[d] * H[(size_t)s*KN + d];
    part += __shfl_xor(part, 1);
    part += __shfl_xor(part, 2);
    part += __shfl_xor(part, 4);
    part += __shfl_xor(part, 8);
    part += __shfl_xor(part, 16);
    if (e == 0) {
        float interf = part + VAR_F;
        float valid  = p[s] * H[(size_t)s*KN + s];
        out[s] = -log1pf(valid / interf) * 1.4426950408889634f;
    }
}

extern "C" void kernel_launch(void* const* d_in, const int* in_sizes, int n_in,
                              void* d_out, int out_size, void* d_ws, size_t ws_size,
                              hipStream_t stream) {
    const float* x         = (const float*)d_in[0];
    const float* edge_attr = (const float*)d_in[1];
    const float* H         = (const float*)d_in[2];
    const int*   edge_idx  = (const int*)  d_in[3];
    const float* Wm1 = (const float*)d_in[4];
    const float* bm1 = (const float*)d_in[5];
    const float* Wm2 = (const float*)d_in[6];
    const float* bm2 = (const float*)d_in[7];
    const float* Wu1 = (const float*)d_in[8];
    const float* bu1 = (const float*)d_in[9];
    const float* Wu2 = (const float*)d_in[10];
    const float* bu2 = (const float*)d_in[11];
    const float* Wh1 = (const float*)d_in[12];
    const float* bh1 = (const float*)d_in[13];
    const float* Wh2 = (const float*)d_in[14];
    const float* bh2 = (const float*)d_in[15];
    float* out = (float*)d_out;
    float* p_ws = (float*)d_ws;   // KN floats

    mpnn_fused<<<KN/4, 256, 0, stream>>>(x, edge_attr, Wm1, bm1, Wm2, bm2,
                                         Wu1, bu1, Wu2, bu2, Wh1, bh1, Wh2, bh2,
                                         p_ws);
    mpnn_interf<<<(KN*DEG)/256, 256, 0, stream>>>(H, edge_idx, p_ws, out);
}

// Round 2
// 31.441 us; speedup vs baseline: 1.8362x; 1.8362x over previous
//
#include <hip/hip_runtime.h>
#include <hip/hip_bf16.h>
#include <math.h>

#define KN 8192
#define DEG 32
#define EE (KN*DEG)

// VAR = float32(10^(-19.9) * 5000000 / 10)
#define VAR_F 6.294627058970831e-15f

typedef __attribute__((ext_vector_type(8)))  short bf16x8;
typedef __attribute__((ext_vector_type(16))) float f32x16;

__device__ __forceinline__ short bf_hi(float f) {
    __hip_bfloat16 h = __float2bfloat16(f);
    return __builtin_bit_cast(short, h);
}
__device__ __forceinline__ float bf_f(short s) {
    __hip_bfloat16 h = __builtin_bit_cast(__hip_bfloat16, s);
    return __bfloat162float(h);
}

// Kernel 1: fused 3x conv + head. ONE wave (64 lanes) per node, 1-wave blocks.
// col = lane&31 : edge index e (A rows), msg channel i (B/D cols)
// g   = lane>>5 : MFMA K-half group
// msg GEMM (32e x 32i x 32j) done as mfma_f32_32x32x16_bf16 with hi/lo
// 3-term split for ~fp32 precision. B (=Wm2) fragments built once.
__global__ __launch_bounds__(64) void mpnn_fused(
    const float* __restrict__ x,
    const float* __restrict__ edge_attr,
    const float* __restrict__ Wm1, const float* __restrict__ bm1,
    const float* __restrict__ Wm2, const float* __restrict__ bm2,
    const float* __restrict__ Wu1, const float* __restrict__ bu1,
    const float* __restrict__ Wu2, const float* __restrict__ bu2,
    const float* __restrict__ Wh1, const float* __restrict__ bh1,
    const float* __restrict__ Wh2, const float* __restrict__ bh2,
    float* __restrict__ p_out)
{
    __shared__ __align__(16) float c_lds[32];
    __shared__ float xt[44];    // [0..8]=x, [9..40]=aggr
    __shared__ float ubuf[16];

    const int lane = threadIdx.x;
    const int col  = lane & 31;
    const int g    = lane >> 5;
    const int k    = blockIdx.x;

    // ---- per-node constants ----
    const float a_e = edge_attr[k*32 + col];          // edge e = col

    // Wm1 rows 0..8 (for c_j, j = col)
    float wm1[9];
    #pragma unroll
    for (int d = 0; d < 9; ++d) wm1[d] = Wm1[k*320 + d*32 + col];
    const float bm1_i = bm1[k*32 + col];
    const float bm2_i = bm2[k*32 + col];

    // Wm1 row 9 at this lane's 16 A-fragment j's: j = s*16 + g*8 + i
    float w9v[16];
    #pragma unroll
    for (int t = 0; t < 16; ++t) {
        int j = (t >> 3)*16 + g*8 + (t & 7);
        w9v[t] = Wm1[k*320 + 288 + j];
    }

    // B fragments: B[kk][col] = Wm2[j][col], kk = s*16 + g*8 + i  (built ONCE)
    bf16x8 Bhi[2], Blo[2];
    #pragma unroll
    for (int s = 0; s < 2; ++s) {
        #pragma unroll
        for (int i = 0; i < 8; ++i) {
            int j = s*16 + g*8 + i;
            float wv = Wm2[k*1024 + j*32 + col];
            short h = bf_hi(wv);
            Bhi[s][i] = h;
            Blo[s][i] = bf_hi(wv - bf_f(h));
        }
    }

    // update-MLP weights
    const int m  = lane & 15;
    const int dg = lane >> 4;        // 0..3
    float wu1[11];
    #pragma unroll
    for (int t = 0; t < 11; ++t) {
        int d = dg*11 + t;
        wu1[t] = (d < 41) ? Wu1[k*656 + d*16 + m] : 0.f;
    }
    const float bu1_m = bu1[k*16 + m];

    const int o  = lane & 7;
    const int mg = lane >> 3;        // 0..7
    const float wu2a = Wu2[k*128 + (mg*2+0)*8 + o];
    const float wu2b = Wu2[k*128 + (mg*2+1)*8 + o];
    const float bu2_o = bu2[k*8 + o];

    float wh1[8];
    #pragma unroll
    for (int d = 0; d < 8; ++d) wh1[d] = Wh1[k*128 + d*16 + m];
    const float bh1_m = bh1[k*16 + m];
    const float wh2_m = Wh2[k*16 + m];
    const float bh2_k = bh2[k];

    if (lane < 9) xt[lane] = x[k*9 + lane];
    __syncthreads();

    for (int it = 0; it < 3; ++it) {
        // c_j = bm1_j + sum_d x_d Wm1[d][j]  (lane computes j = col)
        float c = bm1_i;
        #pragma unroll
        for (int d = 0; d < 9; ++d) c = fmaf(xt[d], wm1[d], c);
        if (g == 0) c_lds[col] = c;
        __syncthreads();

        // A fragments: A[e=col][kk=s*16+g*8+i] = relu(c_j + a_e*Wm1[9][j])
        const float4* cb = (const float4*)c_lds;
        float4 q0 = cb[g*2 + 0];
        float4 q1 = cb[g*2 + 1];
        float4 q2 = cb[4 + g*2 + 0];
        float4 q3 = cb[4 + g*2 + 1];
        float cv[16] = {q0.x,q0.y,q0.z,q0.w, q1.x,q1.y,q1.z,q1.w,
                        q2.x,q2.y,q2.z,q2.w, q3.x,q3.y,q3.z,q3.w};
        bf16x8 Ahi[2], Alo[2];
        #pragma unroll
        for (int s = 0; s < 2; ++s) {
            #pragma unroll
            for (int i = 0; i < 8; ++i) {
                int t = s*8 + i;
                float hv = fmaxf(fmaf(a_e, w9v[t], cv[t]), 0.f);
                short h = bf_hi(hv);
                Ahi[s][i] = h;
                Alo[s][i] = bf_hi(hv - bf_f(h));
            }
        }

        // msg GEMM: D[e][i] = sum_j h[e][j] Wm2[j][i]
        f32x16 acc;
        #pragma unroll
        for (int r = 0; r < 16; ++r) acc[r] = 0.f;
        #pragma unroll
        for (int s = 0; s < 2; ++s) {
            acc = __builtin_amdgcn_mfma_f32_32x32x16_bf16(Ahi[s], Bhi[s], acc, 0, 0, 0);
            acc = __builtin_amdgcn_mfma_f32_32x32x16_bf16(Ahi[s], Blo[s], acc, 0, 0, 0);
            acc = __builtin_amdgcn_mfma_f32_32x32x16_bf16(Alo[s], Bhi[s], acc, 0, 0, 0);
        }

        // aggr_i = sum_e relu(bm2_i + D[e][i]); lane holds col i, 16 rows
        float ag = 0.f;
        #pragma unroll
        for (int r = 0; r < 16; ++r) ag += fmaxf(acc[r] + bm2_i, 0.f);
        ag += __shfl_xor(ag, 32);
        __syncthreads();           // c_lds reads done before xt update races
        if (g == 0) xt[9 + col] = ag;
        __syncthreads();

        // u_m = relu(bu1_m + sum_{d<41} t_d Wu1[d][m]); t = [x(9), aggr(32)]
        float up = 0.f;
        #pragma unroll
        for (int t = 0; t < 11; ++t) {
            int d = dg*11 + t;
            if (d < 41) up = fmaf(xt[d], wu1[t], up);
        }
        up += __shfl_xor(up, 16);
        up += __shfl_xor(up, 32);
        float u = fmaxf(up + bu1_m, 0.f);
        if (lane < 16) ubuf[lane] = u;
        __syncthreads();

        // comb_o = relu(bu2_o + sum_m u_m Wu2[m][o])
        float cp = wu2a * ubuf[mg*2] + wu2b * ubuf[mg*2 + 1];
        cp += __shfl_xor(cp, 8);
        cp += __shfl_xor(cp, 16);
        cp += __shfl_xor(cp, 32);
        float comb = fmaxf(cp + bu2_o, 0.f);
        if (lane < 8) xt[1 + lane] = comb;   // x_new = [x0, comb]
        __syncthreads();
    }

    // head
    float hp = 0.f;
    #pragma unroll
    for (int d = 0; d < 8; ++d) hp = fmaf(xt[1 + d], wh1[d], hp);
    float hh = fmaxf(hp + bh1_m, 0.f);
    float pp = hh * wh2_m;
    pp += __shfl_xor(pp, 1);
    pp += __shfl_xor(pp, 2);
    pp += __shfl_xor(pp, 4);
    pp += __shfl_xor(pp, 8);
    float z = pp + bh2_k;
    float p = 1.f / (1.f + expf(-z));
    if (lane == 0) p_out[k] = p;
}

// Kernel 2: interference + rate. 32 lanes per node.
__global__ __launch_bounds__(256) void mpnn_interf(
    const float* __restrict__ H,
    const int* __restrict__ edge_index,
    const float* __restrict__ p,
    float* __restrict__ out)
{
    const int t = blockIdx.x * 256 + threadIdx.x;
    const int s = t >> 5;
    const int e = t & 31;
    const int* dst = edge_index + EE;
    const int d = dst[s*DEG + e];
    float part = p[d] * H[(size_t)s*KN + d];
    part += __shfl_xor(part, 1);
    part += __shfl_xor(part, 2);
    part += __shfl_xor(part, 4);
    part += __shfl_xor(part, 8);
    part += __shfl_xor(part, 16);
    if (e == 0) {
        float interf = part + VAR_F;
        float valid  = p[s] * H[(size_t)s*KN + s];
        out[s] = -log1pf(valid / interf) * 1.4426950408889634f;
    }
}

extern "C" void kernel_launch(void* const* d_in, const int* in_sizes, int n_in,
                              void* d_out, int out_size, void* d_ws, size_t ws_size,
                              hipStream_t stream) {
    const float* x         = (const float*)d_in[0];
    const float* edge_attr = (const float*)d_in[1];
    const float* H         = (const float*)d_in[2];
    const int*   edge_idx  = (const int*)  d_in[3];
    const float* Wm1 = (const float*)d_in[4];
    const float* bm1 = (const float*)d_in[5];
    const float* Wm2 = (const float*)d_in[6];
    const float* bm2 = (const float*)d_in[7];
    const float* Wu1 = (const float*)d_in[8];
    const float* bu1 = (const float*)d_in[9];
    const float* Wu2 = (const float*)d_in[10];
    const float* bu2 = (const float*)d_in[11];
    const float* Wh1 = (const float*)d_in[12];
    const float* bh1 = (const float*)d_in[13];
    const float* Wh2 = (const float*)d_in[14];
    const float* bh2 = (const float*)d_in[15];
    float* out = (float*)d_out;
    float* p_ws = (float*)d_ws;   // KN floats

    mpnn_fused<<<KN, 64, 0, stream>>>(x, edge_attr, Wm1, bm1, Wm2, bm2,
                                      Wu1, bu1, Wu2, bu2, Wh1, bh1, Wh2, bh2,
                                      p_ws);
    mpnn_interf<<<(KN*DEG)/256, 256, 0, stream>>>(H, edge_idx, p_ws, out);
}